// Round 10
// baseline (2179.813 us; speedup 1.0000x reference)
//
#include <hip/hip_runtime.h>

// Clipped shallow PLRNN — ONE-barrier wave-local pipeline.
// z_{t+1} = A*z_t + (relu(z@W2+h2) - relu(z@W2)) @ W1 + h1 ; x_t = z_t@OB + Ob
// n_states=64, n_hidden=256, bs=256, nt=4096. One row per CU (256 WGs x 256 thr).
//
// Round-9 finding: 2 barriers + lockstep LDS bursts = ~500 cyc/step bubbles.
// Restructure: phase1 (thread tid -> phi[tid]) keeps phi chunk [64w..64w+63]
// INSIDE wave w; phase2 re-mapped so wave w reduces its OWN chunk for ALL 64
// outputs (lane l ends with partial of output l). phi handoff + z copy are
// wave-local (ds_write -> lgkmcnt -> ds_read, NO barrier). Only the 4 partial
// vectors cross waves: ONE barrier/step; z_new computed redundantly per wave
// into a private zsh[w] copy. part[] double-buffered (t&1) against wave lap.

#define NS 64
#define NH 256
#define BS 256

typedef float v2f __attribute__((ext_vector_type(2)));

#define PIN(x) asm volatile("" : "+v"(x))
// LDS-only waits (never drain vmcnt for the fire-and-forget X stores)
#define LGKM0() asm volatile("s_waitcnt lgkmcnt(0)" ::: "memory")
#define BAR()   asm volatile("s_waitcnt lgkmcnt(0)\ns_barrier" ::: "memory")

__device__ __forceinline__ float dppx1(float x) {  // quad_perm [1,0,3,2] == xor 1
    return __int_as_float(__builtin_amdgcn_mov_dpp(__float_as_int(x), 0xB1, 0xF, 0xF, true));
}
__device__ __forceinline__ float dppx2(float x) {  // quad_perm [2,3,0,1] == xor 2
    return __int_as_float(__builtin_amdgcn_mov_dpp(__float_as_int(x), 0x4E, 0xF, 0xF, true));
}

__global__ __launch_bounds__(256) __attribute__((amdgpu_waves_per_eu(1, 1)))
void plrnn_kernel(const float* __restrict__ z0,
                  const float* __restrict__ A,
                  const float* __restrict__ W1,   // [NH][NS]
                  const float* __restrict__ W2,   // [NS][NH]
                  const float* __restrict__ h1,
                  const float* __restrict__ h2,
                  const float* __restrict__ OB,   // [NS][NS]
                  const float* __restrict__ Ob,
                  const int* __restrict__ ntp,
                  float* __restrict__ X)          // [BS][nt+1][NS]
{
    const int b    = blockIdx.x;
    const int tid  = threadIdx.x;
    const int g    = tid >> 2;     // phase1/obs output index (hidden quad / obs out)
    const int s    = tid & 3;      // slice index 0..3 (phase1, obs, AND phase2)
    const int w    = tid >> 6;     // wave
    const int lane = tid & 63;
    const int o4   = lane >> 2;    // phase2 output quad: outputs 4*o4..4*o4+3
    const int nt   = *ntp;
    const bool s1  = (s & 1) != 0;
    const bool s2b = (s & 2) != 0;

    // per-wave private buffers (wave-local handoffs, no barrier needed)
    __shared__ __align__(16) float zsh[4][72];     // z copy per wave (row 288B, 16B-aligned)
    __shared__ __align__(16) float phiL[4][72];    // phi chunk [64w..64w+63] per wave
    __shared__ __align__(16) float part[2][4][68]; // phase2 partials, double-buffered

    // ---- weights in registers, packed in pairs along the reduction dim ----
    v2f w2p[4][8];   // w2p[j][k2] = {W2[16s+2k2][4g+j], W2[16s+2k2+1][4g+j]}
    #pragma unroll
    for (int k2 = 0; k2 < 8; ++k2) {
        const int r0 = 16 * s + 2 * k2;
        const float4 a0 = *reinterpret_cast<const float4*>(&W2[(r0 + 0) * NH + 4 * g]);
        const float4 a1 = *reinterpret_cast<const float4*>(&W2[(r0 + 1) * NH + 4 * g]);
        w2p[0][k2] = (v2f){a0.x, a1.x};
        w2p[1][k2] = (v2f){a0.y, a1.y};
        w2p[2][k2] = (v2f){a0.z, a1.z};
        w2p[3][k2] = (v2f){a0.w, a1.w};
    }
    v2f w1p[4][8];   // w1p[j][t2] = {W1[64w+16s+2t2][4o4+j], W1[64w+16s+2t2+1][4o4+j]}
    #pragma unroll
    for (int t2 = 0; t2 < 8; ++t2) {
        const int r0 = 64 * w + 16 * s + 2 * t2;
        const float4 a0 = *reinterpret_cast<const float4*>(&W1[(r0 + 0) * NS + 4 * o4]);
        const float4 a1 = *reinterpret_cast<const float4*>(&W1[(r0 + 1) * NS + 4 * o4]);
        w1p[0][t2] = (v2f){a0.x, a1.x};
        w1p[1][t2] = (v2f){a0.y, a1.y};
        w1p[2][t2] = (v2f){a0.z, a1.z};
        w1p[3][t2] = (v2f){a0.w, a1.w};
    }
    v2f obp[8];      // obp[k2] = {OB[16s+2k2][g], OB[16s+2k2+1][g]}
    #pragma unroll
    for (int k2 = 0; k2 < 8; ++k2)
        obp[k2] = (v2f){OB[(16 * s + 2 * k2) * NS + g], OB[(16 * s + 2 * k2 + 1) * NS + g]};

    #pragma unroll
    for (int j = 0; j < 4; ++j) {
        #pragma unroll
        for (int k = 0; k < 8; ++k) { PIN(w2p[j][k]); PIN(w1p[j][k]); }
    }
    #pragma unroll
    for (int k = 0; k < 8; ++k) PIN(obp[k]);

    const float hA  = A[lane];     // z_new computed per-lane, replicated per wave
    const float hh1 = h1[lane];
    const float hh2 = h2[tid];     // phi of hidden unit tid
    const float hOb = Ob[g];
    float zcur = z0[b * NS + lane];

    zsh[w][lane] = zcur;           // private copy; wave-local visibility only
    LGKM0();

    float* __restrict__ Xb = X + (size_t)b * (size_t)(nt + 1) * NS;
    const float4* zs4 = reinterpret_cast<const float4*>(&zsh[w][16 * s]);
    const float4* ph4 = reinterpret_cast<const float4*>(&phiL[w][16 * s]);

    for (int t = 0; t < nt; ++t) {
        const int pb = t & 1;

        // ---- z slice s from OWN wave's copy (4x b128, broadcast, 2-way free) ----
        const float4 za = zs4[0], zb = zs4[1], zc = zs4[2], zd = zs4[3];
        const v2f zz2[8] = {{za.x, za.y}, {za.z, za.w}, {zb.x, zb.y}, {zb.z, zb.w},
                            {zc.x, zc.y}, {zc.z, zc.w}, {zd.x, zd.y}, {zd.z, zd.w}};

        // ---- phase1: hidden outputs 4g..4g+3 over slice s ----
        v2f q0 = {0.f, 0.f}, q1 = {0.f, 0.f}, q2 = {0.f, 0.f}, q3 = {0.f, 0.f};
        #pragma unroll
        for (int k2 = 0; k2 < 8; ++k2) {
            q0 = __builtin_elementwise_fma(zz2[k2], w2p[0][k2], q0);
            q1 = __builtin_elementwise_fma(zz2[k2], w2p[1][k2], q1);
            q2 = __builtin_elementwise_fma(zz2[k2], w2p[2][k2], q2);
            q3 = __builtin_elementwise_fma(zz2[k2], w2p[3][k2], q3);
        }
        const float p0 = q0.x + q0.y, p1 = q1.x + q1.y, p2 = q2.x + q2.y, p3 = q3.x + q3.y;

        // quad reduce-scatter -> W2z for hidden unit tid
        float sA = s1 ? p0 : p1;  float rA = dppx1(sA);  float k0 = (s1 ? p1 : p0) + rA;
        float sB = s1 ? p2 : p3;  float rB = dppx1(sB);  float k1 = (s1 ? p3 : p2) + rB;
        float sC = s2b ? k0 : k1; float rC = dppx2(sC);  float W2z = (s2b ? k1 : k0) + rC;

        const float ph = fmaxf(W2z + hh2, 0.f) - fmaxf(W2z, 0.f);
        phiL[w][lane] = ph;                       // wave-local handoff (chunk 64w..64w+63)

        // ---- obs (uses zz2 regs), fire-and-forget store ----
        v2f xop = {0.f, 0.f};
        #pragma unroll
        for (int k2 = 0; k2 < 8; ++k2) xop = __builtin_elementwise_fma(zz2[k2], obp[k2], xop);
        float xr = xop.x + xop.y;
        xr += dppx1(xr);
        xr += dppx2(xr);
        if (s == 0) Xb[(size_t)t * NS + g] = xr + hOb;

        LGKM0();                                  // phi visible to own wave (no barrier)

        // ---- phase2: OWN wave's phi chunk, outputs 4*o4..4*o4+3 over slice s ----
        const float4 f0 = ph4[0], f1 = ph4[1], f2 = ph4[2], f3 = ph4[3];
        const v2f ff[8] = {{f0.x, f0.y}, {f0.z, f0.w}, {f1.x, f1.y}, {f1.z, f1.w},
                           {f2.x, f2.y}, {f2.z, f2.w}, {f3.x, f3.y}, {f3.z, f3.w}};
        v2f u0 = {0.f, 0.f}, u1 = {0.f, 0.f}, u2 = {0.f, 0.f}, u3 = {0.f, 0.f};
        #pragma unroll
        for (int t2 = 0; t2 < 8; ++t2) {
            u0 = __builtin_elementwise_fma(ff[t2], w1p[0][t2], u0);
            u1 = __builtin_elementwise_fma(ff[t2], w1p[1][t2], u1);
            u2 = __builtin_elementwise_fma(ff[t2], w1p[2][t2], u2);
            u3 = __builtin_elementwise_fma(ff[t2], w1p[3][t2], u3);
        }
        const float v0 = u0.x + u0.y, v1 = u1.x + u1.y, v2 = u2.x + u2.y, v3 = u3.x + u3.y;

        // quad reduce-scatter over s -> lane holds partial of output `lane` over chunk w
        float tA = s1 ? v0 : v1;  float wA = dppx1(tA);  float kA = (s1 ? v1 : v0) + wA;
        float tB = s1 ? v2 : v3;  float wB = dppx1(tB);  float kB = (s1 ? v3 : v2) + wB;
        float tC = s2b ? kA : kB; float wC = dppx2(tC);  float Pp = (s2b ? kB : kA) + wC;

        part[pb][w][lane] = Pp;

        BAR();                                    // THE one barrier: partials cross waves

        const float c0 = part[pb][0][lane];
        const float c1 = part[pb][1][lane];
        const float c2 = part[pb][2][lane];
        const float c3 = part[pb][3][lane];

        zcur = fmaf(hA, zcur, (c0 + c1) + (c2 + c3) + hh1);  // replicated on all waves
        zsh[w][lane] = zcur;                      // refresh OWN wave's z copy
        LGKM0();                                  // visible before next-iter zs4 reads
    }

    // ---- final observation x_nt ----
    {
        const float4 za = zs4[0], zb = zs4[1], zc = zs4[2], zd = zs4[3];
        const v2f zz2[8] = {{za.x, za.y}, {za.z, za.w}, {zb.x, zb.y}, {zb.z, zb.w},
                            {zc.x, zc.y}, {zc.z, zc.w}, {zd.x, zd.y}, {zd.z, zd.w}};
        v2f xop = {0.f, 0.f};
        #pragma unroll
        for (int k2 = 0; k2 < 8; ++k2) xop = __builtin_elementwise_fma(zz2[k2], obp[k2], xop);
        float xr = xop.x + xop.y;
        xr += dppx1(xr);
        xr += dppx2(xr);
        if (s == 0) Xb[(size_t)nt * NS + g] = xr + hOb;
    }
}

extern "C" void kernel_launch(void* const* d_in, const int* in_sizes, int n_in,
                              void* d_out, int out_size, void* d_ws, size_t ws_size,
                              hipStream_t stream) {
    const float* z0 = (const float*)d_in[0];
    const float* A  = (const float*)d_in[1];
    const float* W1 = (const float*)d_in[2];
    const float* W2 = (const float*)d_in[3];
    const float* h1 = (const float*)d_in[4];
    const float* h2 = (const float*)d_in[5];
    const float* OB = (const float*)d_in[6];
    const float* Ob = (const float*)d_in[7];
    const int*   ntp = (const int*)d_in[8];
    float* X = (float*)d_out;

    plrnn_kernel<<<BS, 256, 0, stream>>>(z0, A, W1, W2, h1, h2, OB, Ob, ntp, X);
}